// Round 10
// baseline (803.986 us; speedup 1.0000x reference)
//
#include <hip/hip_runtime.h>
#include <hip/hip_bf16.h>
#include <math.h>

#define NN 50000
#define EE 640000
#define DD 128
#define NREL 8
#define NCLS 16
#define NBLK 782                        // ceil(NN/64)
#define NBUCKP (NBLK * 512)             // 400384 padded buckets, key = blk*512 + r*64 + vl
#define SCAN_NBP (NBUCKP / 256)         // 1564 (exact)
#define NBIN 64

typedef __attribute__((ext_vector_type(8))) short short8;   // 8 bf16 = 4 VGPRs
typedef __attribute__((ext_vector_type(4))) float f32x4;    // MFMA acc

__device__ __forceinline__ float bflo(unsigned u) { return __uint_as_float(u << 16); }
__device__ __forceinline__ float bfhi(unsigned u) { return __uint_as_float(u & 0xffff0000u); }
__device__ __forceinline__ float bf2f(ushort u) { return __uint_as_float(((unsigned)u) << 16); }
__device__ __forceinline__ ushort f2b(float f) {  // RNE
  unsigned u = __float_as_uint(f);
  u += 0x7fff + ((u >> 16) & 1);
  return (ushort)(u >> 16);
}
__device__ __forceinline__ int bkey(int dst, int r) {
  return (dst >> 6) * 512 + r * 64 + (dst & 63);
}

// ---------- CSR build ----------

__global__ __launch_bounds__(256) void count_kernel(const int* __restrict__ ei,
                                                    const int* __restrict__ et,
                                                    int* __restrict__ cnt) {
  int t = blockIdx.x * 256 + threadIdx.x;
  if (t < EE) atomicAdd(&cnt[bkey(ei[EE + t], et[t])], 1);
}

__global__ __launch_bounds__(256) void scan1_kernel(const int* __restrict__ cnt,
                                                    int* __restrict__ off,
                                                    int* __restrict__ bsum) {
  __shared__ int s[256];
  const int tid = threadIdx.x;
  const int i = blockIdx.x * 256 + tid;
  int v = (i < NBUCKP) ? cnt[i] : 0;
  s[tid] = v;
  __syncthreads();
#pragma unroll
  for (int o = 1; o < 256; o <<= 1) {
    int t2 = (tid >= o) ? s[tid - o] : 0;
    __syncthreads();
    s[tid] += t2;
    __syncthreads();
  }
  if (i < NBUCKP) off[i] = s[tid] - v;
  if (tid == 255) bsum[blockIdx.x] = s[255];
}

__global__ __launch_bounds__(256) void scan2_kernel(const int* __restrict__ bsum,
                                                    int* __restrict__ bpre) {
  __shared__ int s[256];
  __shared__ int carry;
  const int tid = threadIdx.x;
  if (tid == 0) carry = 0;
  __syncthreads();
  const int chunks = (SCAN_NBP + 255) / 256;
  for (int c = 0; c < chunks; c++) {
    int idx = c * 256 + tid;
    int v = (idx < SCAN_NBP) ? bsum[idx] : 0;
    s[tid] = v;
    __syncthreads();
#pragma unroll
    for (int o = 1; o < 256; o <<= 1) {
      int t2 = (tid >= o) ? s[tid - o] : 0;
      __syncthreads();
      s[tid] += t2;
      __syncthreads();
    }
    if (idx < SCAN_NBP) bpre[idx] = carry + s[tid] - v;
    __syncthreads();
    if (tid == 255) carry += s[255];
    __syncthreads();
  }
}

__global__ __launch_bounds__(256) void scan3_kernel(int* __restrict__ off,
                                                    const int* __restrict__ bpre,
                                                    int* __restrict__ cursor,
                                                    int* __restrict__ hist) {
  int i = blockIdx.x * 256 + threadIdx.x;
  if (i < NBUCKP) {
    int o = off[i] + bpre[i >> 8];
    off[i] = o;
    cursor[i] = o;
  }
  if (i < NBIN) hist[i] = 0;
  if (i == 0) off[NBUCKP] = EE;
}

// rec word0 = src | vl<<16 ; word1 = ew/cnt (pre-divided mean scale)
__global__ __launch_bounds__(256) void bucket_kernel(const int* __restrict__ ei,
                                                     const int* __restrict__ et,
                                                     const float* __restrict__ ew,
                                                     const int* __restrict__ cnt,
                                                     int* __restrict__ cursor,
                                                     uint2* __restrict__ rec) {
  int e = blockIdx.x * 256 + threadIdx.x;
  if (e >= EE) return;
  int dst = ei[EE + e];
  int key = bkey(dst, et[e]);
  float scale = ew[e] / fmaxf((float)cnt[key], 1.0f);
  int pos = atomicAdd(&cursor[key], 1);
  rec[pos] = make_uint2((unsigned)ei[e] | ((unsigned)(dst & 63) << 16),
                        __float_as_uint(scale));
}

// ---------- node-degree counting sort -> vqueue ----------

__device__ __forceinline__ int node_deg(const int* off, int v) {
  int blk = v >> 6, vl = v & 63, d = 0;
#pragma unroll
  for (int r = 0; r < NREL; r++) {
    int k = blk * 512 + r * 64 + vl;
    d += off[k + 1] - off[k];
  }
  return d;
}

__global__ __launch_bounds__(256) void vhist_kernel(const int* __restrict__ off,
                                                    int* __restrict__ hist) {
  __shared__ int lh[NBIN];
  const int tid = threadIdx.x;
  if (tid < NBIN) lh[tid] = 0;
  __syncthreads();
  int v = blockIdx.x * 256 + tid;
  if (v < NN) atomicAdd(&lh[min(node_deg(off, v), NBIN - 1)], 1);
  __syncthreads();
  if (tid < NBIN && lh[tid] > 0) atomicAdd(&hist[tid], lh[tid]);
}

__global__ __launch_bounds__(256) void scan64_kernel(const int* __restrict__ hist,
                                                     int* __restrict__ binCur) {
  __shared__ int s[NBIN];
  const int tid = threadIdx.x;
  if (tid < NBIN) s[tid] = hist[tid];
  __syncthreads();
#pragma unroll
  for (int o = 1; o < NBIN; o <<= 1) {
    int t2 = (tid < NBIN && tid >= o) ? s[tid - o] : 0;
    __syncthreads();
    if (tid < NBIN) s[tid] += t2;
    __syncthreads();
  }
  if (tid < NBIN) binCur[tid] = s[tid] - hist[tid];
}

__global__ __launch_bounds__(256) void vqbuild_kernel(const int* __restrict__ off,
                                                      int* __restrict__ binCur,
                                                      int* __restrict__ vqueue) {
  __shared__ int lh[NBIN];
  __shared__ int lbase[NBIN];
  const int tid = threadIdx.x;
  const int v = blockIdx.x * 256 + tid;
  int bin = -1, lpos = 0;
  if (tid < NBIN) lh[tid] = 0;
  __syncthreads();
  if (v < NN) {
    bin = min(node_deg(off, v), NBIN - 1);
    lpos = atomicAdd(&lh[bin], 1);
  }
  __syncthreads();
  if (tid < NBIN && lh[tid] > 0) lbase[tid] = atomicAdd(&binCur[tid], lh[tid]);
  __syncthreads();
  if (bin >= 0) vqueue[lbase[bin] + lpos] = v;
}

// ---------- pack x (bf16) + W1Tc + W2T ----------
// W1Tc[n*1024 + r*128 + k] = bf16(W1[r][k][n]); W2T[j*128 + k] = bf16(W2[j>>4][k][j&15])
#define XQ (NN * DD / 4)
__global__ __launch_bounds__(256) void pack_kernel(const float* __restrict__ x,
                                                   const float* __restrict__ W1,
                                                   const float* __restrict__ W2,
                                                   ushort* __restrict__ xb,
                                                   ushort* __restrict__ W1Tc,
                                                   ushort* __restrict__ W2T) {
  int t = blockIdx.x * 256 + threadIdx.x;
  if (t < XQ) {
    float4 v = *(const float4*)&x[(size_t)t * 4];
    *(ushort4*)&xb[(size_t)t * 4] = make_ushort4(f2b(v.x), f2b(v.y), f2b(v.z), f2b(v.w));
  } else if (t < XQ + NREL * DD * DD) {
    int t2 = t - XQ;
    int n = t2 >> 10, r = (t2 >> 7) & 7, k = t2 & 127;
    W1Tc[t2] = f2b(W1[r * 16384 + k * 128 + n]);
  } else if (t < XQ + NREL * DD * DD + DD * DD) {
    int t2 = t - XQ - NREL * DD * DD;
    int j = t2 >> 7, k = t2 & 127;
    W2T[t2] = f2b(W2[(j >> 4) * (DD * NCLS) + k * NCLS + (j & 15)]);
  }
}

// ---------- fused layer1+layer2: H2 = bf16( relu(gather(x) @ W1cat) @ W2T^T ) ----------
// Block = 64 nodes. Per relation: edge-parallel scatter — 8 half-waves each own
// one edge/iter: coalesced 256B row read + 4 ds_add_f32/lane into fp32 LDS acc
// (8 independent edges in flight/wave, pipelined). MFMA reads acc w/ bf16 cvt.
// Then relu epilogue + fused layer-2 GEMM on the in-LDS tile.
#define ASF_STRIDE 132
__global__ __launch_bounds__(256) void fused1_kernel(const int* __restrict__ off,
                                                     const uint2* __restrict__ rec,
                                                     const ushort* __restrict__ xb,
                                                     const ushort* __restrict__ W1Tc,
                                                     const ushort* __restrict__ W2T,
                                                     ushort* __restrict__ H2) {
  __shared__ __align__(16) float AsF[64 * ASF_STRIDE];  // 33792 B; reused as ushort[64*136]
  __shared__ ushort Bs[128 * 136];                      // 34816 B
  ushort* AsU = (ushort*)AsF;

  const int tid = threadIdx.x;
  const int m0 = blockIdx.x * 64;
  const int wave = tid >> 6, lane = tid & 63;
  const int lm = lane & 15, lkb = (lane >> 4) * 8;
  const int hw = tid >> 5;        // half-wave 0..7
  const int l = tid & 31;         // lane in half-wave

  f32x4 acc[4][2];
#pragma unroll
  for (int m = 0; m < 4; m++)
#pragma unroll
    for (int j = 0; j < 2; j++) acc[m][j] = (f32x4){0.f, 0.f, 0.f, 0.f};

  for (int r = 0; r < NREL; r++) {
    __syncthreads();  // previous chunk's AsF/Bs reads complete
    // zero fp32 accumulator (2112 float4)
#pragma unroll
    for (int i = 0; i < 9; i++) {
      int idx = i * 256 + tid;
      if (idx < 64 * ASF_STRIDE / 4)
        *(float4*)&AsF[idx * 4] = make_float4(0.f, 0.f, 0.f, 0.f);
    }
    // stage W1Tc slice for relation r
#pragma unroll
    for (int i = 0; i < 8; i++) {
      int seg = tid + i * 256;
      int row = seg >> 4, c8 = (seg & 15) * 8;
      *(uint4*)&Bs[row * 136 + c8] =
          *(const uint4*)&W1Tc[(size_t)row * 1024 + r * 128 + c8];
    }
    __syncthreads();  // zeros + Bs visible
    // edge-parallel scatter over the (block, r) contiguous range
    const int s0 = off[blockIdx.x * 512 + r * 64];
    const int L = off[blockIdx.x * 512 + r * 64 + 64] - s0;
    for (int base = 0; base < L; base += 8) {
      int e = base + hw;
      if (e < L) {
        uint2 q = rec[s0 + e];
        float sc = __uint_as_float(q.y);
        int src = q.x & 0xffff;
        int dl = q.x >> 16;
        const uint* xr = (const uint*)&xb[(size_t)src * DD];
        uint u0 = xr[l];        // cols 2l, 2l+1
        uint u1 = xr[l + 32];   // cols 64+2l, 64+2l+1
        float* ap = &AsF[dl * ASF_STRIDE];
        atomicAdd(&ap[2 * l], sc * bflo(u0));
        atomicAdd(&ap[2 * l + 1], sc * bfhi(u0));
        atomicAdd(&ap[64 + 2 * l], sc * bflo(u1));
        atomicAdd(&ap[64 + 2 * l + 1], sc * bfhi(u1));
      }
    }
    __syncthreads();  // scatter complete
    // MFMA on this chunk (A from fp32 LDS, cvt to bf16 per fragment)
#pragma unroll
    for (int k0 = 0; k0 < 128; k0 += 32) {
      short8 a[4];
#pragma unroll
      for (int m = 0; m < 4; m++) {
        const float* ap = &AsF[(m * 16 + lm) * ASF_STRIDE + k0 + lkb];
        float4 f0 = *(const float4*)ap;
        float4 f1 = *(const float4*)(ap + 4);
        short8 av;
        av[0] = (short)f2b(f0.x); av[1] = (short)f2b(f0.y);
        av[2] = (short)f2b(f0.z); av[3] = (short)f2b(f0.w);
        av[4] = (short)f2b(f1.x); av[5] = (short)f2b(f1.y);
        av[6] = (short)f2b(f1.z); av[7] = (short)f2b(f1.w);
        a[m] = av;
      }
#pragma unroll
      for (int j = 0; j < 2; j++) {
        short8 b = *(const short8*)&Bs[((wave * 2 + j) * 16 + lm) * 136 + k0 + lkb];
#pragma unroll
        for (int m = 0; m < 4; m++)
          acc[m][j] = __builtin_amdgcn_mfma_f32_16x16x32_bf16(a[m], b, acc[m][j], 0, 0, 0);
      }
    }
  }

  // ---- epilogue 1: relu -> bf16 A2 tile in LDS ----
  __syncthreads();
  const int rquad = (lane >> 4) * 4;
#pragma unroll
  for (int m = 0; m < 4; m++)
#pragma unroll
    for (int j = 0; j < 2; j++)
#pragma unroll
      for (int i = 0; i < 4; i++)
        AsU[(m * 16 + rquad + i) * 136 + wave * 32 + j * 16 + lm] =
            f2b(fmaxf(acc[m][j][i], 0.f));
  __syncthreads();

  // ---- layer-2 GEMM on the in-LDS A2 tile ----
#pragma unroll
  for (int i = 0; i < 8; i++) {
    int seg = tid + i * 256;
    int row = seg >> 4, c8 = (seg & 15) * 8;
    *(uint4*)&Bs[row * 136 + c8] = *(const uint4*)&W2T[(size_t)row * DD + c8];
  }
  __syncthreads();
  f32x4 acc2[4][2];
#pragma unroll
  for (int m = 0; m < 4; m++)
#pragma unroll
    for (int j = 0; j < 2; j++) acc2[m][j] = (f32x4){0.f, 0.f, 0.f, 0.f};
#pragma unroll
  for (int k0 = 0; k0 < 128; k0 += 32) {
    short8 a[4];
#pragma unroll
    for (int m = 0; m < 4; m++)
      a[m] = *(const short8*)&AsU[(m * 16 + lm) * 136 + k0 + lkb];
#pragma unroll
    for (int j = 0; j < 2; j++) {
      short8 b = *(const short8*)&Bs[((wave * 2 + j) * 16 + lm) * 136 + k0 + lkb];
#pragma unroll
      for (int m = 0; m < 4; m++)
        acc2[m][j] = __builtin_amdgcn_mfma_f32_16x16x32_bf16(a[m], b, acc2[m][j], 0, 0, 0);
    }
  }
  __syncthreads();
#pragma unroll
  for (int m = 0; m < 4; m++)
#pragma unroll
    for (int j = 0; j < 2; j++)
#pragma unroll
      for (int i = 0; i < 4; i++)
        AsU[(m * 16 + rquad + i) * 136 + wave * 32 + j * 16 + lm] = f2b(acc2[m][j][i]);
  __syncthreads();
#pragma unroll
  for (int i = 0; i < 4; i++) {
    int seg = tid + i * 256;
    int row = seg >> 4, c8 = (seg & 15) * 8;
    int gr = m0 + row;
    if (gr < NN) *(uint4*)&H2[(size_t)gr * DD + c8] = *(const uint4*)&AsU[row * 136 + c8];
  }
}

// ---------- gather2 + log_softmax ----------
// 16 nodes/block from degree-sorted queue; 16 lanes/node walk the node's 8
// bucket ranges; coalesced 32B H2 slices; no atomics; fused log-softmax.
__global__ __launch_bounds__(256) void gather2_kernel(const int* __restrict__ off,
                                                      const uint2* __restrict__ rec,
                                                      const ushort* __restrict__ H2,
                                                      const int* __restrict__ vqueue,
                                                      float* __restrict__ out) {
  const int tid = threadIdx.x;
  const int g = tid >> 4, c = tid & 15;
  const int qi = blockIdx.x * 16 + g;
  float acc = 0.f;
  int v = 0;
  if (qi < NN) {
    v = vqueue[qi];
    const int blk = v >> 6, vl = v & 63;
#pragma unroll
    for (int r = 0; r < NREL; r++) {
      int key = blk * 512 + r * 64 + vl;
      int s = off[key], e = off[key + 1];
      for (int j = s; j < e; j++) {
        uint2 q = rec[j];
        acc = fmaf(__uint_as_float(q.y),
                   bf2f(H2[(size_t)(q.x & 0xffff) * DD + r * NCLS + c]), acc);
      }
    }
  }
  float m = acc;
#pragma unroll
  for (int mask = 8; mask >= 1; mask >>= 1) m = fmaxf(m, __shfl_xor(m, mask, 16));
  float ex = expf(acc - m);
#pragma unroll
  for (int mask = 8; mask >= 1; mask >>= 1) ex += __shfl_xor(ex, mask, 16);
  if (qi < NN) out[(size_t)v * NCLS + c] = acc - m - logf(ex);
}

extern "C" void kernel_launch(void* const* d_in, const int* in_sizes, int n_in,
                              void* d_out, int out_size, void* d_ws, size_t ws_size,
                              hipStream_t stream) {
  const float* x  = (const float*)d_in[0];
  const int*   ei = (const int*)d_in[1];
  const int*   et = (const int*)d_in[2];
  const float* ew = (const float*)d_in[3];
  const float* W1 = (const float*)d_in[4];
  const float* W2 = (const float*)d_in[5];
  float* out = (float*)d_out;
  float* ws = (float*)d_ws;

  // workspace layout (float-unit offsets; ~36 MB)
  int*    cnt    = (int*)ws;                    // 400384
  int*    off    = (int*)(ws + 400384);         // 400385
  int*    bsum   = (int*)(ws + 800772);         // 1564
  int*    bpre   = (int*)(ws + 802336);         // 1564
  int*    cursor = (int*)(ws + 803904);         // 400384
  int*    hist   = (int*)(ws + 1204288);        // 64
  int*    binCur = (int*)(ws + 1204352);        // 64
  int*    vqueue = (int*)(ws + 1204416);        // 50000
  uint2*  rec    = (uint2*)(ws + 1254416);      // 640000 uint2
  ushort* xb     = (ushort*)(ws + 2534416);     // NN*DD bf16
  ushort* W1Tc   = (ushort*)(ws + 5734416);     // 128*1024 bf16
  ushort* W2T    = (ushort*)(ws + 5799952);     // 128*128 bf16
  ushort* H2     = (ushort*)(ws + 5808144);     // NN*DD bf16

  hipMemsetAsync(cnt, 0, (size_t)NBUCKP * sizeof(int), stream);

  count_kernel<<<(EE + 255) / 256, 256, 0, stream>>>(ei, et, cnt);
  scan1_kernel<<<SCAN_NBP, 256, 0, stream>>>(cnt, off, bsum);
  scan2_kernel<<<1, 256, 0, stream>>>(bsum, bpre);
  scan3_kernel<<<SCAN_NBP, 256, 0, stream>>>(off, bpre, cursor, hist);
  bucket_kernel<<<(EE + 255) / 256, 256, 0, stream>>>(ei, et, ew, cnt, cursor, rec);

  vhist_kernel<<<(NN + 255) / 256, 256, 0, stream>>>(off, hist);
  scan64_kernel<<<1, 256, 0, stream>>>(hist, binCur);
  vqbuild_kernel<<<(NN + 255) / 256, 256, 0, stream>>>(off, binCur, vqueue);

  const int packN = XQ + NREL * DD * DD + DD * DD;
  pack_kernel<<<(packN + 255) / 256, 256, 0, stream>>>(x, W1, W2, xb, W1Tc, W2T);

  fused1_kernel<<<NBLK, 256, 0, stream>>>(off, rec, xb, W1Tc, W2T, H2);
  gather2_kernel<<<(NN + 15) / 16, 256, 0, stream>>>(off, rec, H2, vqueue, out);
}

// Round 11
// 278.152 us; speedup vs baseline: 2.8905x; 2.8905x over previous
//
#include <hip/hip_runtime.h>
#include <hip/hip_bf16.h>
#include <math.h>

#define NN 50000
#define EE 640000
#define DD 128
#define NREL 8
#define NCLS 16
#define NBUCK (NREL * NN)              // 400000 buckets, key = dst*8 + rel (dst-major)
#define SCAN_NB ((NBUCK + 255) / 256)  // 1563
#define NBIN 64

typedef __attribute__((ext_vector_type(8))) short short8;   // 8 bf16 = 4 VGPRs
typedef __attribute__((ext_vector_type(4))) float f32x4;    // MFMA acc

__device__ __forceinline__ float bflo(unsigned u) { return __uint_as_float(u << 16); }
__device__ __forceinline__ float bfhi(unsigned u) { return __uint_as_float(u & 0xffff0000u); }
__device__ __forceinline__ float bf2f(ushort u) { return __uint_as_float(((unsigned)u) << 16); }
__device__ __forceinline__ ushort f2b(float f) {  // RNE
  unsigned u = __float_as_uint(f);
  u += 0x7fff + ((u >> 16) & 1);
  return (ushort)(u >> 16);
}

// ---------- CSR build (key = dst*8 + rel) ----------

__global__ __launch_bounds__(256) void count_kernel(const int* __restrict__ ei,
                                                    const int* __restrict__ et,
                                                    int* __restrict__ cnt) {
  int t = blockIdx.x * 256 + threadIdx.x;
  if (t < EE) {
    int key = ei[EE + t] * NREL + et[t];
    atomicAdd(&cnt[key], 1);
  }
}

__global__ __launch_bounds__(256) void scan1_kernel(const int* __restrict__ cnt,
                                                    int* __restrict__ off,
                                                    int* __restrict__ bsum) {
  __shared__ int s[256];
  const int tid = threadIdx.x;
  const int i = blockIdx.x * 256 + tid;
  int v = (i < NBUCK) ? cnt[i] : 0;
  s[tid] = v;
  __syncthreads();
#pragma unroll
  for (int o = 1; o < 256; o <<= 1) {
    int t2 = (tid >= o) ? s[tid - o] : 0;
    __syncthreads();
    s[tid] += t2;
    __syncthreads();
  }
  if (i < NBUCK) off[i] = s[tid] - v;
  if (tid == 255) bsum[blockIdx.x] = s[255];
}

__global__ __launch_bounds__(256) void scan2_kernel(const int* __restrict__ bsum,
                                                    int* __restrict__ bpre) {
  __shared__ int s[256];
  __shared__ int carry;
  const int tid = threadIdx.x;
  if (tid == 0) carry = 0;
  __syncthreads();
  const int chunks = (SCAN_NB + 255) / 256;
  for (int c = 0; c < chunks; c++) {
    int idx = c * 256 + tid;
    int v = (idx < SCAN_NB) ? bsum[idx] : 0;
    s[tid] = v;
    __syncthreads();
#pragma unroll
    for (int o = 1; o < 256; o <<= 1) {
      int t2 = (tid >= o) ? s[tid - o] : 0;
      __syncthreads();
      s[tid] += t2;
      __syncthreads();
    }
    if (idx < SCAN_NB) bpre[idx] = carry + s[tid] - v;
    __syncthreads();
    if (tid == 255) carry += s[255];
    __syncthreads();
  }
}

// finalizes off, fills cursor, zeroes the degree-bin histogram
__global__ __launch_bounds__(256) void scan3_kernel(int* __restrict__ off,
                                                    const int* __restrict__ bpre,
                                                    int* __restrict__ cursor,
                                                    int* __restrict__ hist) {
  int i = blockIdx.x * 256 + threadIdx.x;
  if (i < NBUCK) {
    int o = off[i] + bpre[i >> 8];
    off[i] = o;
    cursor[i] = o;
  }
  if (i < NBIN) hist[i] = 0;
  if (i == 0) off[NBUCK] = EE;
}

// rec word0 = src | rel<<16 ; word1 = ew/cnt (pre-divided mean scale)
__global__ __launch_bounds__(256) void bucket_kernel(const int* __restrict__ ei,
                                                     const int* __restrict__ et,
                                                     const float* __restrict__ ew,
                                                     const int* __restrict__ cnt,
                                                     int* __restrict__ cursor,
                                                     uint2* __restrict__ rec) {
  int e = blockIdx.x * 256 + threadIdx.x;
  if (e >= EE) return;
  int r = et[e];
  int key = ei[EE + e] * NREL + r;
  float scale = ew[e] / fmaxf((float)cnt[key], 1.0f);
  int pos = atomicAdd(&cursor[key], 1);
  rec[pos] = make_uint2((unsigned)ei[e] | ((unsigned)r << 16), __float_as_uint(scale));
}

// ---------- node-degree counting sort -> vqueue ----------

__global__ __launch_bounds__(256) void vhist_kernel(const int* __restrict__ off,
                                                    int* __restrict__ hist) {
  __shared__ int lh[NBIN];
  const int tid = threadIdx.x;
  if (tid < NBIN) lh[tid] = 0;
  __syncthreads();
  int v = blockIdx.x * 256 + tid;
  if (v < NN) {
    int deg = off[v * NREL + NREL] - off[v * NREL];
    atomicAdd(&lh[min(deg, NBIN - 1)], 1);
  }
  __syncthreads();
  if (tid < NBIN && lh[tid] > 0) atomicAdd(&hist[tid], lh[tid]);
}

__global__ __launch_bounds__(256) void scan64_kernel(const int* __restrict__ hist,
                                                     int* __restrict__ binCur) {
  __shared__ int s[NBIN];
  const int tid = threadIdx.x;
  if (tid < NBIN) s[tid] = hist[tid];
  __syncthreads();
#pragma unroll
  for (int o = 1; o < NBIN; o <<= 1) {
    int t2 = (tid < NBIN && tid >= o) ? s[tid - o] : 0;
    __syncthreads();
    if (tid < NBIN) s[tid] += t2;
    __syncthreads();
  }
  if (tid < NBIN) binCur[tid] = s[tid] - hist[tid];
}

__global__ __launch_bounds__(256) void vqbuild_kernel(const int* __restrict__ off,
                                                      int* __restrict__ binCur,
                                                      int* __restrict__ vqueue) {
  __shared__ int lh[NBIN];
  __shared__ int lbase[NBIN];
  const int tid = threadIdx.x;
  const int v = blockIdx.x * 256 + tid;
  int bin = -1, lpos = 0;
  if (tid < NBIN) lh[tid] = 0;
  __syncthreads();
  if (v < NN) {
    int deg = off[v * NREL + NREL] - off[v * NREL];
    bin = min(deg, NBIN - 1);
    lpos = atomicAdd(&lh[bin], 1);
  }
  __syncthreads();
  if (tid < NBIN && lh[tid] > 0) lbase[tid] = atomicAdd(&binCur[tid], lh[tid]);
  __syncthreads();
  if (bin >= 0) vqueue[lbase[bin] + lpos] = v;
}

// ---------- pack x (bf16) + W1Tc + W2T ----------
// W1Tc[n*1024 + r*128 + k] = bf16(W1[r][k][n]); W2T[j*128 + k] = bf16(W2[j>>4][k][j&15])
#define XQ (NN * DD / 4)
__global__ __launch_bounds__(256) void pack_kernel(const float* __restrict__ x,
                                                   const float* __restrict__ W1,
                                                   const float* __restrict__ W2,
                                                   ushort* __restrict__ xb,
                                                   ushort* __restrict__ W1Tc,
                                                   ushort* __restrict__ W2T) {
  int t = blockIdx.x * 256 + threadIdx.x;
  if (t < XQ) {
    float4 v = *(const float4*)&x[(size_t)t * 4];
    *(ushort4*)&xb[(size_t)t * 4] = make_ushort4(f2b(v.x), f2b(v.y), f2b(v.z), f2b(v.w));
  } else if (t < XQ + NREL * DD * DD) {
    int t2 = t - XQ;
    int n = t2 >> 10, r = (t2 >> 7) & 7, k = t2 & 127;
    W1Tc[t2] = f2b(W1[r * 16384 + k * 128 + n]);
  } else if (t < XQ + NREL * DD * DD + DD * DD) {
    int t2 = t - XQ - NREL * DD * DD;
    int j = t2 >> 7, k = t2 & 127;
    W2T[t2] = f2b(W2[(j >> 4) * (DD * NCLS) + k * NCLS + (j & 15)]);
  }
}

// ---------- fused layer1+layer2: H2 = bf16( relu(gather(x) @ W1cat) @ W2T^T ) ----------
// Block = 64 nodes, LDS = A-tile only (17.4 KB). Per relation r (unrolled):
// register gather (4 thr/node x 32 cols, 2 edges in flight) -> bf16 tile in LDS
// -> MFMA with B fragments loaded straight from L2 (W1Tc is L2-resident).
// Then relu epilogue + layer-2 GEMM (W2T also from L2). A2 never touches HBM.
__global__ __launch_bounds__(256) void fused1_kernel(const int* __restrict__ off,
                                                     const uint2* __restrict__ rec,
                                                     const ushort* __restrict__ xb,
                                                     const ushort* __restrict__ W1Tc,
                                                     const ushort* __restrict__ W2T,
                                                     ushort* __restrict__ H2) {
  __shared__ ushort AsU[64 * 136];     // 17408 B total LDS
  const int tid = threadIdx.x;
  const int m0 = blockIdx.x * 64;
  const int wave = tid >> 6, lane = tid & 63;
  const int lm = lane & 15, lkb = (lane >> 4) * 8;
  const int gn = tid >> 2;          // gather: node 0..63
  const int gc = (tid & 3) * 32;    // gather: col base
  const int v = m0 + gn;

  // hoist the node's 9 contiguous offsets (dst-major key)
  int offv[9];
  if (v < NN) {
    int4 o0 = *(const int4*)&off[v * 8];
    int4 o1 = *(const int4*)&off[v * 8 + 4];
    offv[0] = o0.x; offv[1] = o0.y; offv[2] = o0.z; offv[3] = o0.w;
    offv[4] = o1.x; offv[5] = o1.y; offv[6] = o1.z; offv[7] = o1.w;
    offv[8] = off[v * 8 + 8];
  } else {
#pragma unroll
    for (int i = 0; i < 9; i++) offv[i] = 0;
  }

  f32x4 acc[4][2];
#pragma unroll
  for (int m = 0; m < 4; m++)
#pragma unroll
    for (int j = 0; j < 2; j++) acc[m][j] = (f32x4){0.f, 0.f, 0.f, 0.f};

#pragma unroll
  for (int r = 0; r < NREL; r++) {
    __syncthreads();  // previous chunk's AsU reads complete
    // register gather, 2 edges in flight
    float g[32];
#pragma unroll
    for (int j = 0; j < 32; j++) g[j] = 0.f;
    {
      int s = offv[r], e = offv[r + 1];
      int i = s;
      for (; i + 2 <= e; i += 2) {
        uint2 q0 = rec[i], q1 = rec[i + 1];
        float sc0 = __uint_as_float(q0.y), sc1 = __uint_as_float(q1.y);
        const ushort* xr0 = &xb[(size_t)(q0.x & 0xffff) * DD + gc];
        const ushort* xr1 = &xb[(size_t)(q1.x & 0xffff) * DD + gc];
        uint4 h0[4], h1[4];
#pragma unroll
        for (int jj = 0; jj < 4; jj++) h0[jj] = *(const uint4*)&xr0[jj * 8];
#pragma unroll
        for (int jj = 0; jj < 4; jj++) h1[jj] = *(const uint4*)&xr1[jj * 8];
#pragma unroll
        for (int jj = 0; jj < 4; jj++) {
          float* gg = &g[jj * 8];
          gg[0] = fmaf(sc0, bflo(h0[jj].x), gg[0]);
          gg[1] = fmaf(sc0, bfhi(h0[jj].x), gg[1]);
          gg[2] = fmaf(sc0, bflo(h0[jj].y), gg[2]);
          gg[3] = fmaf(sc0, bfhi(h0[jj].y), gg[3]);
          gg[4] = fmaf(sc0, bflo(h0[jj].z), gg[4]);
          gg[5] = fmaf(sc0, bfhi(h0[jj].z), gg[5]);
          gg[6] = fmaf(sc0, bflo(h0[jj].w), gg[6]);
          gg[7] = fmaf(sc0, bfhi(h0[jj].w), gg[7]);
          gg[0] = fmaf(sc1, bflo(h1[jj].x), gg[0]);
          gg[1] = fmaf(sc1, bfhi(h1[jj].x), gg[1]);
          gg[2] = fmaf(sc1, bflo(h1[jj].y), gg[2]);
          gg[3] = fmaf(sc1, bfhi(h1[jj].y), gg[3]);
          gg[4] = fmaf(sc1, bflo(h1[jj].z), gg[4]);
          gg[5] = fmaf(sc1, bfhi(h1[jj].z), gg[5]);
          gg[6] = fmaf(sc1, bflo(h1[jj].w), gg[6]);
          gg[7] = fmaf(sc1, bfhi(h1[jj].w), gg[7]);
        }
      }
      if (i < e) {
        uint2 q = rec[i];
        float sc = __uint_as_float(q.y);
        const ushort* xr = &xb[(size_t)(q.x & 0xffff) * DD + gc];
#pragma unroll
        for (int jj = 0; jj < 4; jj++) {
          uint4 h = *(const uint4*)&xr[jj * 8];
          float* gg = &g[jj * 8];
          gg[0] = fmaf(sc, bflo(h.x), gg[0]);
          gg[1] = fmaf(sc, bfhi(h.x), gg[1]);
          gg[2] = fmaf(sc, bflo(h.y), gg[2]);
          gg[3] = fmaf(sc, bfhi(h.y), gg[3]);
          gg[4] = fmaf(sc, bflo(h.z), gg[4]);
          gg[5] = fmaf(sc, bfhi(h.z), gg[5]);
          gg[6] = fmaf(sc, bflo(h.w), gg[6]);
          gg[7] = fmaf(sc, bfhi(h.w), gg[7]);
        }
      }
    }
#pragma unroll
    for (int jj = 0; jj < 4; jj++) {
      uint4 u;
      u.x = (unsigned)f2b(g[jj * 8 + 0]) | ((unsigned)f2b(g[jj * 8 + 1]) << 16);
      u.y = (unsigned)f2b(g[jj * 8 + 2]) | ((unsigned)f2b(g[jj * 8 + 3]) << 16);
      u.z = (unsigned)f2b(g[jj * 8 + 4]) | ((unsigned)f2b(g[jj * 8 + 5]) << 16);
      u.w = (unsigned)f2b(g[jj * 8 + 6]) | ((unsigned)f2b(g[jj * 8 + 7]) << 16);
      *(uint4*)&AsU[gn * 136 + gc + jj * 8] = u;
    }
    __syncthreads();
    // MFMA on this chunk; B fragments straight from L2-resident W1Tc
#pragma unroll
    for (int k0 = 0; k0 < 128; k0 += 32) {
      short8 b0 = *(const short8*)&W1Tc[(size_t)((wave * 2 + 0) * 16 + lm) * 1024 + r * 128 + k0 + lkb];
      short8 b1 = *(const short8*)&W1Tc[(size_t)((wave * 2 + 1) * 16 + lm) * 1024 + r * 128 + k0 + lkb];
      short8 a[4];
#pragma unroll
      for (int m = 0; m < 4; m++)
        a[m] = *(const short8*)&AsU[(m * 16 + lm) * 136 + k0 + lkb];
#pragma unroll
      for (int m = 0; m < 4; m++)
        acc[m][0] = __builtin_amdgcn_mfma_f32_16x16x32_bf16(a[m], b0, acc[m][0], 0, 0, 0);
#pragma unroll
      for (int m = 0; m < 4; m++)
        acc[m][1] = __builtin_amdgcn_mfma_f32_16x16x32_bf16(a[m], b1, acc[m][1], 0, 0, 0);
    }
  }

  // ---- epilogue 1: relu -> bf16 A2 tile in LDS ----
  __syncthreads();
  const int rquad = (lane >> 4) * 4;
#pragma unroll
  for (int m = 0; m < 4; m++)
#pragma unroll
    for (int j = 0; j < 2; j++)
#pragma unroll
      for (int i = 0; i < 4; i++)
        AsU[(m * 16 + rquad + i) * 136 + wave * 32 + j * 16 + lm] =
            f2b(fmaxf(acc[m][j][i], 0.f));
  __syncthreads();

  // ---- layer-2 GEMM on the in-LDS A2 tile (W2T from L2) ----
  f32x4 acc2[4][2];
#pragma unroll
  for (int m = 0; m < 4; m++)
#pragma unroll
    for (int j = 0; j < 2; j++) acc2[m][j] = (f32x4){0.f, 0.f, 0.f, 0.f};
#pragma unroll
  for (int k0 = 0; k0 < 128; k0 += 32) {
    short8 b0 = *(const short8*)&W2T[(size_t)((wave * 2 + 0) * 16 + lm) * DD + k0 + lkb];
    short8 b1 = *(const short8*)&W2T[(size_t)((wave * 2 + 1) * 16 + lm) * DD + k0 + lkb];
    short8 a[4];
#pragma unroll
    for (int m = 0; m < 4; m++)
      a[m] = *(const short8*)&AsU[(m * 16 + lm) * 136 + k0 + lkb];
#pragma unroll
    for (int m = 0; m < 4; m++)
      acc2[m][0] = __builtin_amdgcn_mfma_f32_16x16x32_bf16(a[m], b0, acc2[m][0], 0, 0, 0);
#pragma unroll
    for (int m = 0; m < 4; m++)
      acc2[m][1] = __builtin_amdgcn_mfma_f32_16x16x32_bf16(a[m], b1, acc2[m][1], 0, 0, 0);
  }
  __syncthreads();
#pragma unroll
  for (int m = 0; m < 4; m++)
#pragma unroll
    for (int j = 0; j < 2; j++)
#pragma unroll
      for (int i = 0; i < 4; i++)
        AsU[(m * 16 + rquad + i) * 136 + wave * 32 + j * 16 + lm] = f2b(acc2[m][j][i]);
  __syncthreads();
#pragma unroll
  for (int i = 0; i < 4; i++) {
    int seg = tid + i * 256;
    int row = seg >> 4, c8 = (seg & 15) * 8;
    int gr = m0 + row;
    if (gr < NN) *(uint4*)&H2[(size_t)gr * DD + c8] = *(const uint4*)&AsU[row * 136 + c8];
  }
}

// ---------- gather2 + log_softmax ----------
// 16 nodes/block from degree-sorted queue; 16 lanes/node walk the node's single
// contiguous edge range (rel tag in rec), 2 edges in flight; coalesced 32B H2
// slices; no atomics; fused log-softmax.
__global__ __launch_bounds__(256) void gather2_kernel(const int* __restrict__ off,
                                                      const uint2* __restrict__ rec,
                                                      const ushort* __restrict__ H2,
                                                      const int* __restrict__ vqueue,
                                                      float* __restrict__ out) {
  const int tid = threadIdx.x;
  const int g = tid >> 4, c = tid & 15;
  const int qi = blockIdx.x * 16 + g;
  float acc = 0.f;
  int v = 0;
  if (qi < NN) {
    v = vqueue[qi];
    const int s = off[v * NREL], e = off[v * NREL + NREL];
    int j = s;
    for (; j + 2 <= e; j += 2) {
      uint2 q0 = rec[j], q1 = rec[j + 1];
      ushort h0 = H2[(size_t)(q0.x & 0xffff) * DD + (q0.x >> 16) * NCLS + c];
      ushort h1 = H2[(size_t)(q1.x & 0xffff) * DD + (q1.x >> 16) * NCLS + c];
      acc = fmaf(__uint_as_float(q0.y), bf2f(h0), acc);
      acc = fmaf(__uint_as_float(q1.y), bf2f(h1), acc);
    }
    if (j < e) {
      uint2 q = rec[j];
      acc = fmaf(__uint_as_float(q.y),
                 bf2f(H2[(size_t)(q.x & 0xffff) * DD + (q.x >> 16) * NCLS + c]), acc);
    }
  }
  float m = acc;
#pragma unroll
  for (int mask = 8; mask >= 1; mask >>= 1) m = fmaxf(m, __shfl_xor(m, mask, 16));
  float ex = expf(acc - m);
#pragma unroll
  for (int mask = 8; mask >= 1; mask >>= 1) ex += __shfl_xor(ex, mask, 16);
  if (qi < NN) out[(size_t)v * NCLS + c] = acc - m - logf(ex);
}

extern "C" void kernel_launch(void* const* d_in, const int* in_sizes, int n_in,
                              void* d_out, int out_size, void* d_ws, size_t ws_size,
                              hipStream_t stream) {
  const float* x  = (const float*)d_in[0];
  const int*   ei = (const int*)d_in[1];
  const int*   et = (const int*)d_in[2];
  const float* ew = (const float*)d_in[3];
  const float* W1 = (const float*)d_in[4];
  const float* W2 = (const float*)d_in[5];
  float* out = (float*)d_out;
  float* ws = (float*)d_ws;

  // workspace layout (float-unit offsets; ~36 MB)
  int*    cnt    = (int*)ws;                    // 400000
  int*    off    = (int*)(ws + 400000);         // 400001 (+pad)
  int*    bsum   = (int*)(ws + 800004);         // 1563 (+pad)
  int*    bpre   = (int*)(ws + 801568);         // 1563 (+pad)
  int*    cursor = (int*)(ws + 803132);         // 400000
  int*    hist   = (int*)(ws + 1203132);        // 64
  int*    binCur = (int*)(ws + 1203196);        // 64
  int*    vqueue = (int*)(ws + 1203260);        // 50000
  uint2*  rec    = (uint2*)(ws + 1253260);      // 640000 uint2
  ushort* xb     = (ushort*)(ws + 2533260);     // NN*DD bf16
  ushort* W1Tc   = (ushort*)(ws + 5733260);     // 128*1024 bf16
  ushort* W2T    = (ushort*)(ws + 5798796);     // 128*128 bf16
  ushort* H2     = (ushort*)(ws + 5806988);     // NN*DD bf16

  hipMemsetAsync(cnt, 0, (size_t)NBUCK * sizeof(int), stream);

  count_kernel<<<(EE + 255) / 256, 256, 0, stream>>>(ei, et, cnt);
  scan1_kernel<<<SCAN_NB, 256, 0, stream>>>(cnt, off, bsum);
  scan2_kernel<<<1, 256, 0, stream>>>(bsum, bpre);
  scan3_kernel<<<SCAN_NB, 256, 0, stream>>>(off, bpre, cursor, hist);
  bucket_kernel<<<(EE + 255) / 256, 256, 0, stream>>>(ei, et, ew, cnt, cursor, rec);

  vhist_kernel<<<(NN + 255) / 256, 256, 0, stream>>>(off, hist);
  scan64_kernel<<<1, 256, 0, stream>>>(hist, binCur);
  vqbuild_kernel<<<(NN + 255) / 256, 256, 0, stream>>>(off, binCur, vqueue);

  const int packN = XQ + NREL * DD * DD + DD * DD;
  pack_kernel<<<(packN + 255) / 256, 256, 0, stream>>>(x, W1, W2, xb, W1Tc, W2T);

  fused1_kernel<<<(NN + 63) / 64, 256, 0, stream>>>(off, rec, xb, W1Tc, W2T, H2);
  gather2_kernel<<<(NN + 15) / 16, 256, 0, stream>>>(off, rec, H2, vqueue, out);
}

// Round 12
// 273.890 us; speedup vs baseline: 2.9354x; 1.0156x over previous
//
#include <hip/hip_runtime.h>
#include <hip/hip_bf16.h>
#include <math.h>

#define NN 50000
#define EE 640000
#define DD 128
#define NREL 8
#define NCLS 16
#define NBUCK (NREL * NN)              // 400000 buckets, key = dst*8 + rel (dst-major)
#define SCAN_NB ((NBUCK + 255) / 256)  // 1563
#define NBIN 64

typedef __attribute__((ext_vector_type(8))) short short8;   // 8 bf16 = 4 VGPRs
typedef __attribute__((ext_vector_type(4))) float f32x4;    // MFMA acc

__device__ __forceinline__ float bflo(unsigned u) { return __uint_as_float(u << 16); }
__device__ __forceinline__ float bfhi(unsigned u) { return __uint_as_float(u & 0xffff0000u); }
__device__ __forceinline__ float bf2f(ushort u) { return __uint_as_float(((unsigned)u) << 16); }
__device__ __forceinline__ ushort f2b(float f) {  // RNE
  unsigned u = __float_as_uint(f);
  u += 0x7fff + ((u >> 16) & 1);
  return (ushort)(u >> 16);
}

// ---------- CSR build (key = dst*8 + rel) ----------

__global__ __launch_bounds__(256) void count_kernel(const int* __restrict__ ei,
                                                    const int* __restrict__ et,
                                                    int* __restrict__ cnt) {
  int t = blockIdx.x * 256 + threadIdx.x;
  if (t < EE) {
    int key = ei[EE + t] * NREL + et[t];
    atomicAdd(&cnt[key], 1);
  }
}

__global__ __launch_bounds__(256) void scan1_kernel(const int* __restrict__ cnt,
                                                    int* __restrict__ off,
                                                    int* __restrict__ bsum) {
  __shared__ int s[256];
  const int tid = threadIdx.x;
  const int i = blockIdx.x * 256 + tid;
  int v = (i < NBUCK) ? cnt[i] : 0;
  s[tid] = v;
  __syncthreads();
#pragma unroll
  for (int o = 1; o < 256; o <<= 1) {
    int t2 = (tid >= o) ? s[tid - o] : 0;
    __syncthreads();
    s[tid] += t2;
    __syncthreads();
  }
  if (i < NBUCK) off[i] = s[tid] - v;
  if (tid == 255) bsum[blockIdx.x] = s[255];
}

__global__ __launch_bounds__(256) void scan2_kernel(const int* __restrict__ bsum,
                                                    int* __restrict__ bpre) {
  __shared__ int s[256];
  __shared__ int carry;
  const int tid = threadIdx.x;
  if (tid == 0) carry = 0;
  __syncthreads();
  const int chunks = (SCAN_NB + 255) / 256;
  for (int c = 0; c < chunks; c++) {
    int idx = c * 256 + tid;
    int v = (idx < SCAN_NB) ? bsum[idx] : 0;
    s[tid] = v;
    __syncthreads();
#pragma unroll
    for (int o = 1; o < 256; o <<= 1) {
      int t2 = (tid >= o) ? s[tid - o] : 0;
      __syncthreads();
      s[tid] += t2;
      __syncthreads();
    }
    if (idx < SCAN_NB) bpre[idx] = carry + s[tid] - v;
    __syncthreads();
    if (tid == 255) carry += s[255];
    __syncthreads();
  }
}

// finalizes off, fills cursor, zeroes the degree-bin histogram
__global__ __launch_bounds__(256) void scan3_kernel(int* __restrict__ off,
                                                    const int* __restrict__ bpre,
                                                    int* __restrict__ cursor,
                                                    int* __restrict__ hist) {
  int i = blockIdx.x * 256 + threadIdx.x;
  if (i < NBUCK) {
    int o = off[i] + bpre[i >> 8];
    off[i] = o;
    cursor[i] = o;
  }
  if (i < NBIN) hist[i] = 0;
  if (i == 0) off[NBUCK] = EE;
}

// rec word0 = src | rel<<16 ; word1 = ew/cnt (pre-divided mean scale)
__global__ __launch_bounds__(256) void bucket_kernel(const int* __restrict__ ei,
                                                     const int* __restrict__ et,
                                                     const float* __restrict__ ew,
                                                     const int* __restrict__ cnt,
                                                     int* __restrict__ cursor,
                                                     uint2* __restrict__ rec) {
  int e = blockIdx.x * 256 + threadIdx.x;
  if (e >= EE) return;
  int r = et[e];
  int key = ei[EE + e] * NREL + r;
  float scale = ew[e] / fmaxf((float)cnt[key], 1.0f);
  int pos = atomicAdd(&cursor[key], 1);
  rec[pos] = make_uint2((unsigned)ei[e] | ((unsigned)r << 16), __float_as_uint(scale));
}

// ---------- node-degree counting sort -> vqueue ----------

__global__ __launch_bounds__(256) void vhist_kernel(const int* __restrict__ off,
                                                    int* __restrict__ hist) {
  __shared__ int lh[NBIN];
  const int tid = threadIdx.x;
  if (tid < NBIN) lh[tid] = 0;
  __syncthreads();
  int v = blockIdx.x * 256 + tid;
  if (v < NN) {
    int deg = off[v * NREL + NREL] - off[v * NREL];
    atomicAdd(&lh[min(deg, NBIN - 1)], 1);
  }
  __syncthreads();
  if (tid < NBIN && lh[tid] > 0) atomicAdd(&hist[tid], lh[tid]);
}

__global__ __launch_bounds__(256) void scan64_kernel(const int* __restrict__ hist,
                                                     int* __restrict__ binCur) {
  __shared__ int s[NBIN];
  const int tid = threadIdx.x;
  if (tid < NBIN) s[tid] = hist[tid];
  __syncthreads();
#pragma unroll
  for (int o = 1; o < NBIN; o <<= 1) {
    int t2 = (tid < NBIN && tid >= o) ? s[tid - o] : 0;
    __syncthreads();
    if (tid < NBIN) s[tid] += t2;
    __syncthreads();
  }
  if (tid < NBIN) binCur[tid] = s[tid] - hist[tid];
}

__global__ __launch_bounds__(256) void vqbuild_kernel(const int* __restrict__ off,
                                                      int* __restrict__ binCur,
                                                      int* __restrict__ vqueue) {
  __shared__ int lh[NBIN];
  __shared__ int lbase[NBIN];
  const int tid = threadIdx.x;
  const int v = blockIdx.x * 256 + tid;
  int bin = -1, lpos = 0;
  if (tid < NBIN) lh[tid] = 0;
  __syncthreads();
  if (v < NN) {
    int deg = off[v * NREL + NREL] - off[v * NREL];
    bin = min(deg, NBIN - 1);
    lpos = atomicAdd(&lh[bin], 1);
  }
  __syncthreads();
  if (tid < NBIN && lh[tid] > 0) lbase[tid] = atomicAdd(&binCur[tid], lh[tid]);
  __syncthreads();
  if (bin >= 0) vqueue[lbase[bin] + lpos] = v;
}

// ---------- pack x (bf16) + W1Tc + W2T ----------
// W1Tc[n*1024 + r*128 + k] = bf16(W1[r][k][n]); W2T[j*128 + k] = bf16(W2[j>>4][k][j&15])
#define XQ (NN * DD / 4)
__global__ __launch_bounds__(256) void pack_kernel(const float* __restrict__ x,
                                                   const float* __restrict__ W1,
                                                   const float* __restrict__ W2,
                                                   ushort* __restrict__ xb,
                                                   ushort* __restrict__ W1Tc,
                                                   ushort* __restrict__ W2T) {
  int t = blockIdx.x * 256 + threadIdx.x;
  if (t < XQ) {
    float4 v = *(const float4*)&x[(size_t)t * 4];
    *(ushort4*)&xb[(size_t)t * 4] = make_ushort4(f2b(v.x), f2b(v.y), f2b(v.z), f2b(v.w));
  } else if (t < XQ + NREL * DD * DD) {
    int t2 = t - XQ;
    int n = t2 >> 10, r = (t2 >> 7) & 7, k = t2 & 127;
    W1Tc[t2] = f2b(W1[r * 16384 + k * 128 + n]);
  } else if (t < XQ + NREL * DD * DD + DD * DD) {
    int t2 = t - XQ - NREL * DD * DD;
    int j = t2 >> 7, k = t2 & 127;
    W2T[t2] = f2b(W2[(j >> 4) * (DD * NCLS) + k * NCLS + (j & 15)]);
  }
}

// ---------- fused layer1+layer2: H2 = bf16( relu(gather(x) @ W1cat) @ W2T^T ) ----------
// Block = 64 nodes, 512 threads (8 waves) for 2x latency-hiding vs R11.
// Gather: 8 thr/node x 16 cols, 2 edges in flight. MFMA: 8 waves x 16 out-cols
// (acc[4][1]), B fragments straight from L2. Layer-2 GEMM fused; A2 never in HBM.
__global__ __launch_bounds__(512) void fused1_kernel(const int* __restrict__ off,
                                                     const uint2* __restrict__ rec,
                                                     const ushort* __restrict__ xb,
                                                     const ushort* __restrict__ W1Tc,
                                                     const ushort* __restrict__ W2T,
                                                     ushort* __restrict__ H2) {
  __shared__ ushort AsU[64 * 136];     // 17408 B total LDS
  const int tid = threadIdx.x;
  const int m0 = blockIdx.x * 64;
  const int wave = tid >> 6, lane = tid & 63;
  const int lm = lane & 15, lkb = (lane >> 4) * 8;
  const int gn = tid >> 3;          // gather: node 0..63
  const int gc = (tid & 7) * 16;    // gather: col base (16 cols)
  const int v = m0 + gn;

  // hoist the node's 9 contiguous offsets (dst-major key)
  int offv[9];
  if (v < NN) {
    int4 o0 = *(const int4*)&off[v * 8];
    int4 o1 = *(const int4*)&off[v * 8 + 4];
    offv[0] = o0.x; offv[1] = o0.y; offv[2] = o0.z; offv[3] = o0.w;
    offv[4] = o1.x; offv[5] = o1.y; offv[6] = o1.z; offv[7] = o1.w;
    offv[8] = off[v * 8 + 8];
  } else {
#pragma unroll
    for (int i = 0; i < 9; i++) offv[i] = 0;
  }

  f32x4 acc[4];
#pragma unroll
  for (int m = 0; m < 4; m++) acc[m] = (f32x4){0.f, 0.f, 0.f, 0.f};

#pragma unroll
  for (int r = 0; r < NREL; r++) {
    __syncthreads();  // previous chunk's AsU reads complete
    // register gather, 2 edges in flight, 16 cols (2 uint4) per edge
    float g[16];
#pragma unroll
    for (int j = 0; j < 16; j++) g[j] = 0.f;
    {
      int s = offv[r], e = offv[r + 1];
      int i = s;
      for (; i + 2 <= e; i += 2) {
        uint2 q0 = rec[i], q1 = rec[i + 1];
        float sc0 = __uint_as_float(q0.y), sc1 = __uint_as_float(q1.y);
        const ushort* xr0 = &xb[(size_t)(q0.x & 0xffff) * DD + gc];
        const ushort* xr1 = &xb[(size_t)(q1.x & 0xffff) * DD + gc];
        uint4 h0[2], h1[2];
#pragma unroll
        for (int jj = 0; jj < 2; jj++) h0[jj] = *(const uint4*)&xr0[jj * 8];
#pragma unroll
        for (int jj = 0; jj < 2; jj++) h1[jj] = *(const uint4*)&xr1[jj * 8];
#pragma unroll
        for (int jj = 0; jj < 2; jj++) {
          float* gg = &g[jj * 8];
          gg[0] = fmaf(sc0, bflo(h0[jj].x), gg[0]);
          gg[1] = fmaf(sc0, bfhi(h0[jj].x), gg[1]);
          gg[2] = fmaf(sc0, bflo(h0[jj].y), gg[2]);
          gg[3] = fmaf(sc0, bfhi(h0[jj].y), gg[3]);
          gg[4] = fmaf(sc0, bflo(h0[jj].z), gg[4]);
          gg[5] = fmaf(sc0, bfhi(h0[jj].z), gg[5]);
          gg[6] = fmaf(sc0, bflo(h0[jj].w), gg[6]);
          gg[7] = fmaf(sc0, bfhi(h0[jj].w), gg[7]);
          gg[0] = fmaf(sc1, bflo(h1[jj].x), gg[0]);
          gg[1] = fmaf(sc1, bfhi(h1[jj].x), gg[1]);
          gg[2] = fmaf(sc1, bflo(h1[jj].y), gg[2]);
          gg[3] = fmaf(sc1, bfhi(h1[jj].y), gg[3]);
          gg[4] = fmaf(sc1, bflo(h1[jj].z), gg[4]);
          gg[5] = fmaf(sc1, bfhi(h1[jj].z), gg[5]);
          gg[6] = fmaf(sc1, bflo(h1[jj].w), gg[6]);
          gg[7] = fmaf(sc1, bfhi(h1[jj].w), gg[7]);
        }
      }
      if (i < e) {
        uint2 q = rec[i];
        float sc = __uint_as_float(q.y);
        const ushort* xr = &xb[(size_t)(q.x & 0xffff) * DD + gc];
#pragma unroll
        for (int jj = 0; jj < 2; jj++) {
          uint4 h = *(const uint4*)&xr[jj * 8];
          float* gg = &g[jj * 8];
          gg[0] = fmaf(sc, bflo(h.x), gg[0]);
          gg[1] = fmaf(sc, bfhi(h.x), gg[1]);
          gg[2] = fmaf(sc, bflo(h.y), gg[2]);
          gg[3] = fmaf(sc, bfhi(h.y), gg[3]);
          gg[4] = fmaf(sc, bflo(h.z), gg[4]);
          gg[5] = fmaf(sc, bfhi(h.z), gg[5]);
          gg[6] = fmaf(sc, bflo(h.w), gg[6]);
          gg[7] = fmaf(sc, bfhi(h.w), gg[7]);
        }
      }
    }
#pragma unroll
    for (int jj = 0; jj < 2; jj++) {
      uint4 u;
      u.x = (unsigned)f2b(g[jj * 8 + 0]) | ((unsigned)f2b(g[jj * 8 + 1]) << 16);
      u.y = (unsigned)f2b(g[jj * 8 + 2]) | ((unsigned)f2b(g[jj * 8 + 3]) << 16);
      u.z = (unsigned)f2b(g[jj * 8 + 4]) | ((unsigned)f2b(g[jj * 8 + 5]) << 16);
      u.w = (unsigned)f2b(g[jj * 8 + 6]) | ((unsigned)f2b(g[jj * 8 + 7]) << 16);
      *(uint4*)&AsU[gn * 136 + gc + jj * 8] = u;
    }
    __syncthreads();
    // MFMA: wave owns out-cols [wave*16, wave*16+16); B fragment from L2
#pragma unroll
    for (int k0 = 0; k0 < 128; k0 += 32) {
      short8 b = *(const short8*)&W1Tc[(size_t)(wave * 16 + lm) * 1024 + r * 128 + k0 + lkb];
      short8 a[4];
#pragma unroll
      for (int m = 0; m < 4; m++)
        a[m] = *(const short8*)&AsU[(m * 16 + lm) * 136 + k0 + lkb];
#pragma unroll
      for (int m = 0; m < 4; m++)
        acc[m] = __builtin_amdgcn_mfma_f32_16x16x32_bf16(a[m], b, acc[m], 0, 0, 0);
    }
  }

  // ---- epilogue 1: relu -> bf16 A2 tile in LDS ----
  __syncthreads();
  const int rquad = (lane >> 4) * 4;
#pragma unroll
  for (int m = 0; m < 4; m++)
#pragma unroll
    for (int i = 0; i < 4; i++)
      AsU[(m * 16 + rquad + i) * 136 + wave * 16 + lm] = f2b(fmaxf(acc[m][i], 0.f));
  __syncthreads();

  // ---- layer-2 GEMM on the in-LDS A2 tile (W2T from L2) ----
  f32x4 acc2[4];
#pragma unroll
  for (int m = 0; m < 4; m++) acc2[m] = (f32x4){0.f, 0.f, 0.f, 0.f};
#pragma unroll
  for (int k0 = 0; k0 < 128; k0 += 32) {
    short8 b = *(const short8*)&W2T[(size_t)(wave * 16 + lm) * DD + k0 + lkb];
    short8 a[4];
#pragma unroll
    for (int m = 0; m < 4; m++)
      a[m] = *(const short8*)&AsU[(m * 16 + lm) * 136 + k0 + lkb];
#pragma unroll
    for (int m = 0; m < 4; m++)
      acc2[m] = __builtin_amdgcn_mfma_f32_16x16x32_bf16(a[m], b, acc2[m], 0, 0, 0);
  }
  __syncthreads();
#pragma unroll
  for (int m = 0; m < 4; m++)
#pragma unroll
    for (int i = 0; i < 4; i++)
      AsU[(m * 16 + rquad + i) * 136 + wave * 16 + lm] = f2b(acc2[m][i]);
  __syncthreads();
#pragma unroll
  for (int i = 0; i < 2; i++) {
    int seg = tid + i * 512;
    int row = seg >> 4, c8 = (seg & 15) * 8;
    int gr = m0 + row;
    if (gr < NN) *(uint4*)&H2[(size_t)gr * DD + c8] = *(const uint4*)&AsU[row * 136 + c8];
  }
}

// ---------- gather2 + log_softmax ----------
// 16 nodes/block from degree-sorted queue; 16 lanes/node walk the node's single
// contiguous edge range (rel tag in rec), 2 edges in flight; coalesced 32B H2
// slices; no atomics; fused log-softmax.
__global__ __launch_bounds__(256) void gather2_kernel(const int* __restrict__ off,
                                                      const uint2* __restrict__ rec,
                                                      const ushort* __restrict__ H2,
                                                      const int* __restrict__ vqueue,
                                                      float* __restrict__ out) {
  const int tid = threadIdx.x;
  const int g = tid >> 4, c = tid & 15;
  const int qi = blockIdx.x * 16 + g;
  float acc = 0.f;
  int v = 0;
  if (qi < NN) {
    v = vqueue[qi];
    const int s = off[v * NREL], e = off[v * NREL + NREL];
    int j = s;
    for (; j + 2 <= e; j += 2) {
      uint2 q0 = rec[j], q1 = rec[j + 1];
      ushort h0 = H2[(size_t)(q0.x & 0xffff) * DD + (q0.x >> 16) * NCLS + c];
      ushort h1 = H2[(size_t)(q1.x & 0xffff) * DD + (q1.x >> 16) * NCLS + c];
      acc = fmaf(__uint_as_float(q0.y), bf2f(h0), acc);
      acc = fmaf(__uint_as_float(q1.y), bf2f(h1), acc);
    }
    if (j < e) {
      uint2 q = rec[j];
      acc = fmaf(__uint_as_float(q.y),
                 bf2f(H2[(size_t)(q.x & 0xffff) * DD + (q.x >> 16) * NCLS + c]), acc);
    }
  }
  float m = acc;
#pragma unroll
  for (int mask = 8; mask >= 1; mask >>= 1) m = fmaxf(m, __shfl_xor(m, mask, 16));
  float ex = expf(acc - m);
#pragma unroll
  for (int mask = 8; mask >= 1; mask >>= 1) ex += __shfl_xor(ex, mask, 16);
  if (qi < NN) out[(size_t)v * NCLS + c] = acc - m - logf(ex);
}

extern "C" void kernel_launch(void* const* d_in, const int* in_sizes, int n_in,
                              void* d_out, int out_size, void* d_ws, size_t ws_size,
                              hipStream_t stream) {
  const float* x  = (const float*)d_in[0];
  const int*   ei = (const int*)d_in[1];
  const int*   et = (const int*)d_in[2];
  const float* ew = (const float*)d_in[3];
  const float* W1 = (const float*)d_in[4];
  const float* W2 = (const float*)d_in[5];
  float* out = (float*)d_out;
  float* ws = (float*)d_ws;

  // workspace layout (float-unit offsets; ~36 MB)
  int*    cnt    = (int*)ws;                    // 400000
  int*    off    = (int*)(ws + 400000);         // 400001 (+pad)
  int*    bsum   = (int*)(ws + 800004);         // 1563 (+pad)
  int*    bpre   = (int*)(ws + 801568);         // 1563 (+pad)
  int*    cursor = (int*)(ws + 803132);         // 400000
  int*    hist   = (int*)(ws + 1203132);        // 64
  int*    binCur = (int*)(ws + 1203196);        // 64
  int*    vqueue = (int*)(ws + 1203260);        // 50000
  uint2*  rec    = (uint2*)(ws + 1253260);      // 640000 uint2
  ushort* xb     = (ushort*)(ws + 2533260);     // NN*DD bf16
  ushort* W1Tc   = (ushort*)(ws + 5733260);     // 128*1024 bf16
  ushort* W2T    = (ushort*)(ws + 5798796);     // 128*128 bf16
  ushort* H2     = (ushort*)(ws + 5806988);     // NN*DD bf16

  hipMemsetAsync(cnt, 0, (size_t)NBUCK * sizeof(int), stream);

  count_kernel<<<(EE + 255) / 256, 256, 0, stream>>>(ei, et, cnt);
  scan1_kernel<<<SCAN_NB, 256, 0, stream>>>(cnt, off, bsum);
  scan2_kernel<<<1, 256, 0, stream>>>(bsum, bpre);
  scan3_kernel<<<SCAN_NB, 256, 0, stream>>>(off, bpre, cursor, hist);
  bucket_kernel<<<(EE + 255) / 256, 256, 0, stream>>>(ei, et, ew, cnt, cursor, rec);

  vhist_kernel<<<(NN + 255) / 256, 256, 0, stream>>>(off, hist);
  scan64_kernel<<<1, 256, 0, stream>>>(hist, binCur);
  vqbuild_kernel<<<(NN + 255) / 256, 256, 0, stream>>>(off, binCur, vqueue);

  const int packN = XQ + NREL * DD * DD + DD * DD;
  pack_kernel<<<(packN + 255) / 256, 256, 0, stream>>>(x, W1, W2, xb, W1Tc, W2T);

  fused1_kernel<<<(NN + 63) / 64, 512, 0, stream>>>(off, rec, xb, W1Tc, W2T, H2);
  gather2_kernel<<<(NN + 15) / 16, 256, 0, stream>>>(off, rec, H2, vqueue, out);
}